// Round 15
// baseline (751.900 us; speedup 1.0000x reference)
//
#include <hip/hip_runtime.h>
#include <hip/hip_bf16.h>

typedef _Float16 f16;
typedef _Float16 f16x8 __attribute__((ext_vector_type(8)));
typedef float f32x4 __attribute__((ext_vector_type(4)));

#define NBATCH 128
#define NTIME  128
#define NKIN   512
#define NUNITS 512
#define NGATE  2048

#define HSZ    (NBATCH * NUNITS)   // one h slot (f16 elems)
#define POISON 0x7C00u             // f16 +inf: impossible as h = o*tanh(c)

static __device__ __forceinline__ float sigmoidf_(float x) {
    return 1.0f / (1.0f + __expf(-x));
}
static __device__ __forceinline__ float tanhf_(float x) {
    float t = __expf(-2.0f * fabsf(x));
    float r = (1.0f - t) / (1.0f + t);
    return copysignf(r, x);
}

static __device__ __forceinline__ f16x8 pack8(float4 a, float4 b) {
    f16x8 r;
    r[0] = (f16)a.x; r[1] = (f16)a.y; r[2] = (f16)a.z; r[3] = (f16)a.w;
    r[4] = (f16)b.x; r[5] = (f16)b.y; r[6] = (f16)b.z; r[7] = (f16)b.w;
    return r;
}

// ---- MALL-coherent (sc0 sc1) ops ----
static __device__ __forceinline__ void store_u16_sys(void* p, unsigned short v) {
    asm volatile("global_store_short %0, %1, off sc0 sc1" :: "v"(p), "v"(v) : "memory");
}
static __device__ __forceinline__ void store_16B_sys(void* p, f32x4 v) {
    asm volatile("global_store_dwordx4 %0, %1, off sc0 sc1" :: "v"(p), "v"(v) : "memory");
}
// probe 4 consecutive 16B A-frag chunks (no wait) — executed FULL-EXEC (all lanes)
static __device__ __forceinline__ void probe4x16_sys(const f16* p, f32x4* a, f32x4* b,
                                                     f32x4* c, f32x4* d) {
    asm volatile("global_load_dwordx4 %0, %4, off sc0 sc1\n\t"
                 "global_load_dwordx4 %1, %4, off offset:64 sc0 sc1\n\t"
                 "global_load_dwordx4 %2, %4, off offset:128 sc0 sc1\n\t"
                 "global_load_dwordx4 %3, %4, off offset:192 sc0 sc1"
                 : "=v"(*a), "=v"(*b), "=v"(*c), "=v"(*d)
                 : "v"(p) : "memory");
}
static __device__ __forceinline__ void wait_vm0_fence() {
    asm volatile("s_waitcnt vmcnt(0)" ::: "memory");
    __builtin_amdgcn_sched_barrier(0);   // rule 18: fence register consumers
}
static __device__ __forceinline__ void drain_stores() {
    asm volatile("s_waitcnt vmcnt(0)" ::: "memory");
}

// true if no f16 half of the 16B chunk equals the poison pattern
static __device__ __forceinline__ int chunk_clean(f32x4 v) {
#pragma unroll
    for (int i = 0; i < 4; ++i) {
        unsigned u = __float_as_uint(v[i]);
        if ((u & 0xFFFFu) == POISON || (u >> 16) == POISON) return 0;
    }
    return 1;
}

// ---------------- poison init: fill 3 h slots with f16 +inf ----------------
__global__ __launch_bounds__(256)
void k_poison(f16* __restrict__ hsl) {
    f32x4 v;
    const float pf = __uint_as_float((POISON << 16) | POISON);
#pragma unroll
    for (int i = 0; i < 4; ++i) v[i] = pf;
    const size_t i = ((size_t)blockIdx.x * 256 + threadIdx.x) * 8;
    if (i < (size_t)3 * HSZ) *(f32x4*)(hsl + i) = v;
}

// ---------------- transpose: f32 in[512][2048] -> f16 out[2048][512] ----------------
__global__ __launch_bounds__(256)
void k_transpose(const float* __restrict__ in, f16* __restrict__ out) {
    __shared__ f16 tile[64][72];
    const int c0 = blockIdx.x * 64;
    const int r0 = blockIdx.y * 64;
    const int tid = threadIdx.x;
    {
        const int lr = tid >> 2;
        const int lc = (tid & 3) << 4;
        const float* src = in + (size_t)(r0 + lr) * NGATE + c0 + lc;
        float4 v0 = ((const float4*)src)[0];
        float4 v1 = ((const float4*)src)[1];
        float4 v2 = ((const float4*)src)[2];
        float4 v3 = ((const float4*)src)[3];
        *(f16x8*)&tile[lr][lc]     = pack8(v0, v1);
        *(f16x8*)&tile[lr][lc + 8] = pack8(v2, v3);
    }
    __syncthreads();
    {
        const int lc = tid >> 2;
        const int lr = (tid & 3) << 4;
        f16x8 a, b;
#pragma unroll
        for (int i = 0; i < 8; ++i) a[i] = tile[lr + i][lc];
#pragma unroll
        for (int i = 0; i < 8; ++i) b[i] = tile[lr + 8 + i][lc];
        f16* dst = out + (size_t)(c0 + lc) * NKIN + r0 + lr;
        *(f16x8*)dst       = a;
        *(f16x8*)(dst + 8) = b;
    }
}

// ---------------- projection: xz[t][b][g] = x[b][t][:] @ W[:][g] + bias[g] ----------------
__global__ __launch_bounds__(256)
void k_proj(const float* __restrict__ x, const f16* __restrict__ Wt,
            const float* __restrict__ bias, f16* __restrict__ xz) {
    __shared__ f16 As[128][40];
    __shared__ f16 Bs[128][40];
    const int bid = blockIdx.y * gridDim.x + blockIdx.x;
    const int swz = (bid & 7) * 256 + (bid >> 3);
    const int nb = swz & 15;
    const int tb = swz >> 4;
    const int n0 = nb * 128;
    const int tid  = threadIdx.x;
    const int lane = tid & 63;
    const int wid  = tid >> 6;
    const int wm = (wid >> 1) * 64;
    const int wn = (wid & 1) * 64;
    const int lm = lane & 15;
    const int lg = lane >> 4;

    f32x4 acc[4][4];
#pragma unroll
    for (int mi = 0; mi < 4; ++mi)
#pragma unroll
        for (int ni = 0; ni < 4; ++ni)
#pragma unroll
            for (int i = 0; i < 4; ++i) acc[mi][ni][i] = 0.0f;

    for (int kt = 0; kt < NKIN; kt += 32) {
        {
            const int brow = tid >> 1;
            const int kq   = (tid & 1) << 4;
            const float* src = x + ((size_t)brow * NTIME + tb) * NKIN + kt + kq;
            float4 v0 = ((const float4*)src)[0];
            float4 v1 = ((const float4*)src)[1];
            float4 v2 = ((const float4*)src)[2];
            float4 v3 = ((const float4*)src)[3];
            *(f16x8*)&As[brow][kq]     = pack8(v0, v1);
            *(f16x8*)&As[brow][kq + 8] = pack8(v2, v3);
        }
        {
            const int nrow = tid >> 1;
            const int kq   = (tid & 1) << 4;
            const f16* src = Wt + (size_t)(n0 + nrow) * NKIN + kt + kq;
            *(f16x8*)&Bs[nrow][kq]     = *(const f16x8*)src;
            *(f16x8*)&Bs[nrow][kq + 8] = *(const f16x8*)(src + 8);
        }
        __syncthreads();
        f16x8 a[4], b[4];
#pragma unroll
        for (int mi = 0; mi < 4; ++mi)
            a[mi] = *(const f16x8*)&As[wm + mi * 16 + lm][lg * 8];
#pragma unroll
        for (int ni = 0; ni < 4; ++ni)
            b[ni] = *(const f16x8*)&Bs[wn + ni * 16 + lm][lg * 8];
#pragma unroll
        for (int mi = 0; mi < 4; ++mi)
#pragma unroll
            for (int ni = 0; ni < 4; ++ni)
                acc[mi][ni] = __builtin_amdgcn_mfma_f32_16x16x32_f16(a[mi], b[ni], acc[mi][ni], 0, 0, 0);
        __syncthreads();
    }
#pragma unroll
    for (int mi = 0; mi < 4; ++mi) {
#pragma unroll
        for (int ni = 0; ni < 4; ++ni) {
            const int col = n0 + wn + ni * 16 + lm;
            const float bv = bias[col];
#pragma unroll
            for (int i = 0; i < 4; ++i) {
                const int brow = wm + mi * 16 + lg * 4 + i;
                xz[((size_t)tb * NBATCH + brow) * NGATE + col] = (f16)(acc[mi][ni][i] + bv);
            }
        }
    }
}

// ---------------- persistent LSTM: barrier-free autonomous wave-agents (v2) ----------
// r14 design with the masked-asm hazard removed: probes run FULL-EXEC (quad lanes
// duplicate addresses; TA coalescing dedupes), and the zero A-rows are re-established
// EXPLICITLY after each poll (plain C masked assignment — any lowering is correct).
// Agent (grp=bid&7, slot=bid>>3, w): rows grp*16+w*4..+3, cols slot*16..+15, all 4
// gates. Valid rows at M-rows {0,4,8,12} -> state is lane-local (acc[0] of each
// gate): no zs, no steady-state barriers. Poison-rotation safety: vmcnt(0) drain
// between step-t poison and h[t] store (r14 reasoning, re-verified).
__global__ __launch_bounds__(256, 1)
void k_lstm(const f16* __restrict__ xz, const f16* __restrict__ Ut,
            f16* __restrict__ hsl, float* __restrict__ out) {
    __shared__ f16 Us[64][512];          // 64 gate-cols x 512 k, XOR-swizzled (64KB)
    __shared__ f16 pad[12 * 1024];       // 24KB -> 88KB total: forces 1 block/CU
    const int bid = blockIdx.x;
    const int grp  = bid & 7;
    const int slot = bid >> 3;
    const int u0 = slot * 16;
    const int tid  = threadIdx.x;
    const int lane = tid & 63;
    const int w    = tid >> 6;
    const int lm = lane & 15;
    const int lg = lane >> 4;
    const int rbase = grp * 16 + w * 4;  // wave's 4 batch rows

    *((volatile f16*)&pad[tid]) = (f16)0;  // keep pad (r9: DSE removed plain pad)

    // one-time: stage 64 U gate-cols into LDS, XOR-swizzled
#pragma unroll
    for (int i = 0; i < 16; ++i) {
        const int idx = tid + i * 256;
        const int c   = idx >> 6;
        const int ck  = idx & 63;
        const int gcol = (c >> 4) * NUNITS + u0 + (c & 15);
        f16x8 v = *(const f16x8*)(Ut + (size_t)gcol * NUNITS + ck * 8);
        *(f16x8*)&Us[c][(ck ^ (c & 7)) * 8] = v;
    }

    const int myrow = rbase + lg;            // lane's output row
    const int gidx = myrow * NUNITS + u0 + lm;
    const int aload = ((lm & 3) == 0);       // lanes whose A-row carries data
    const int arow = rbase + (lm >> 2);      // h row this lane's quad covers
    float c_reg = 0.0f;

    f32x4 pz;
    {
        const float pf = __uint_as_float((POISON << 16) | POISON);
#pragma unroll
        for (int i = 0; i < 4; ++i) pz[i] = pf;
    }

    // A-frag registers (zero rows re-established explicitly each step)
    f32x4 pr[16];
#pragma unroll
    for (int ks = 0; ks < 16; ++ks)
#pragma unroll
        for (int i = 0; i < 4; ++i) pr[ks][i] = 0.0f;

    // xz for t=0: one value per gate for this lane's (row, col)
    float px[4];
#pragma unroll
    for (int g = 0; g < 4; ++g)
        px[g] = (float)xz[(size_t)myrow * NGATE + g * NUNITS + u0 + lm];

    __syncthreads();   // Us ready — the ONLY block barrier

    for (int t = 0; t < NTIME; ++t) {
        f16* hout = hsl + (size_t)(t % 3) * HSZ;

        if (t > 0) {
            // poll h[t-1]: ALL lanes probe (quad-duplicated addresses)
            const f16* ap = hsl + (size_t)((t + 2) % 3) * HSZ
                          + (size_t)arow * NUNITS + lg * 8;
            for (int spin = 0; spin < 65536; ++spin) {
                probe4x16_sys(ap,       &pr[0],  &pr[1],  &pr[2],  &pr[3]);
                probe4x16_sys(ap + 128, &pr[4],  &pr[5],  &pr[6],  &pr[7]);
                probe4x16_sys(ap + 256, &pr[8],  &pr[9],  &pr[10], &pr[11]);
                probe4x16_sys(ap + 384, &pr[12], &pr[13], &pr[14], &pr[15]);
                wait_vm0_fence();
                int clean = 1;
#pragma unroll
                for (int ks = 0; ks < 16; ++ks) clean &= chunk_clean(pr[ks]);
                if (__all(clean)) break;
            }
            // re-establish zero A-rows (plain C masked assignment — robust)
            if (!aload) {
#pragma unroll
                for (int ks = 0; ks < 16; ++ks)
#pragma unroll
                    for (int i = 0; i < 4; ++i) pr[ks][i] = 0.0f;
            }
            // recycle: poison own [4 rows x 16 cols] of slot (t+1)%3 (holds h[t-2];
            // poll success proves all clique readers of it are done)
            if (lane < 8) {
                f16* ps = hsl + (size_t)((t + 1) % 3) * HSZ
                              + (size_t)(rbase + (lane >> 1)) * NUNITS + u0 + (lane & 1) * 8;
                store_16B_sys(ps, pz);
            }
        }

        // MFMA: 4 gate chains (independent), A from pr regs, B from LDS Us
        f32x4 acc0, acc1, acc2, acc3;
        acc0[0] = px[0]; acc1[0] = px[1]; acc2[0] = px[2]; acc3[0] = px[3];
#pragma unroll
        for (int i = 1; i < 4; ++i) { acc0[i] = 0.f; acc1[i] = 0.f; acc2[i] = 0.f; acc3[i] = 0.f; }
#pragma unroll
        for (int ks = 0; ks < 16; ++ks) {
            const f16x8 af = __builtin_bit_cast(f16x8, pr[ks]);
            const int ca = ((ks * 4 + lg) ^ (lm & 7)) * 8;
            acc0 = __builtin_amdgcn_mfma_f32_16x16x32_f16(af, *(const f16x8*)&Us[ 0 + lm][ca], acc0, 0, 0, 0);
            acc1 = __builtin_amdgcn_mfma_f32_16x16x32_f16(af, *(const f16x8*)&Us[16 + lm][ca], acc1, 0, 0, 0);
            acc2 = __builtin_amdgcn_mfma_f32_16x16x32_f16(af, *(const f16x8*)&Us[32 + lm][ca], acc2, 0, 0, 0);
            acc3 = __builtin_amdgcn_mfma_f32_16x16x32_f16(af, *(const f16x8*)&Us[48 + lm][ca], acc3, 0, 0, 0);
        }

        // state: fully lane-local (i,f,g,o all in this lane's acc[0]s)
        const float iv = sigmoidf_(acc0[0]);
        const float fv = sigmoidf_(acc1[0]);
        const float gv = tanhf_(acc2[0]);
        const float ov = sigmoidf_(acc3[0]);
        c_reg = fv * c_reg + iv * gv;
        const float hn = ov * tanhf_(c_reg);

        if (t == NTIME - 1) {
            out[gidx]          = hn;
            out[65536 + gidx]  = hn;
            out[131072 + gidx] = c_reg;
        } else {
            // ORDER: step-t poison must commit before h[t] becomes visible.
            drain_stores();
            union { f16 h; unsigned short u; } cv; cv.h = (f16)hn;
            store_u16_sys(hout + gidx, cv.u);
            // prefetch next xz AFTER the store (drained by next poll's vmcnt(0))
#pragma unroll
            for (int g = 0; g < 4; ++g)
                px[g] = (float)xz[((size_t)(t + 1) * NBATCH + myrow) * NGATE
                                  + g * NUNITS + u0 + lm];
        }
    }
}

extern "C" void kernel_launch(void* const* d_in, const int* in_sizes, int n_in,
                              void* d_out, int out_size, void* d_ws, size_t ws_size,
                              hipStream_t stream) {
    const float* x    = (const float*)d_in[0];
    const float* W    = (const float*)d_in[1];
    const float* U    = (const float*)d_in[2];
    const float* bias = (const float*)d_in[3];
    float* out = (float*)d_out;
    char* ws = (char*)d_ws;

    size_t off = 0;
    f16* Wt = (f16*)(ws + off); off += (size_t)NGATE * NKIN * 2;
    f16* Ut = (f16*)(ws + off); off += (size_t)NGATE * NUNITS * 2;
    f16* xz = (f16*)(ws + off); off += (size_t)NTIME * NBATCH * NGATE * 2;  // [t][b][g]
    f16* hsl = (f16*)(ws + off); off += (size_t)3 * HSZ * 2;                // 3 h slots
    if (ws_size < off) return;

    k_poison<<<dim3(96), 256, 0, stream>>>(hsl);
    k_transpose<<<dim3(32, 8), 256, 0, stream>>>(W, Wt);
    k_transpose<<<dim3(32, 8), 256, 0, stream>>>(U, Ut);
    k_proj<<<dim3(16, 128), 256, 0, stream>>>(x, Wt, bias, xz);
    k_lstm<<<dim3(256), 256, 0, stream>>>(xz, Ut, hsl, out);
}

// Round 16
// 461.115 us; speedup vs baseline: 1.6306x; 1.6306x over previous
//
#include <hip/hip_runtime.h>
#include <hip/hip_bf16.h>

typedef _Float16 f16;
typedef _Float16 f16x8 __attribute__((ext_vector_type(8)));
typedef float f32x4 __attribute__((ext_vector_type(4)));

#define NBATCH 128
#define NTIME  128
#define NKIN   512
#define NUNITS 512
#define NGATE  2048

#define GROUPS 16   // batch groups (8 rows each): grp = bid & 15
#define BLKPG  16   // blocks per group (32 unit-cols each): slot = bid >> 4
#define GROWS  8    // batch rows per group
#define HSZ    (NBATCH * NUNITS)   // one h slot (f16 elems)
#define POISON 0x7C00u             // f16 +inf: impossible as h = o*tanh(c)

static __device__ __forceinline__ float sigmoidf_(float x) {
    return 1.0f / (1.0f + __expf(-x));
}
static __device__ __forceinline__ float tanhf_(float x) {
    float t = __expf(-2.0f * fabsf(x));
    float r = (1.0f - t) / (1.0f + t);
    return copysignf(r, x);
}

static __device__ __forceinline__ f16x8 pack8(float4 a, float4 b) {
    f16x8 r;
    r[0] = (f16)a.x; r[1] = (f16)a.y; r[2] = (f16)a.z; r[3] = (f16)a.w;
    r[4] = (f16)b.x; r[5] = (f16)b.y; r[6] = (f16)b.z; r[7] = (f16)b.w;
    return r;
}

// ---- MALL-coherent (sc0 sc1) ops: bypass L1+L2; device-wide; proven r3/r4/r8 ----
static __device__ __forceinline__ void store_u16_sys(void* p, unsigned short v) {
    asm volatile("global_store_short %0, %1, off sc0 sc1" :: "v"(p), "v"(v) : "memory");
}
static __device__ __forceinline__ void store_16B_sys(void* p, f32x4 v) {
    asm volatile("global_store_dwordx4 %0, %1, off sc0 sc1" :: "v"(p), "v"(v) : "memory");
}
static __device__ __forceinline__ void load2x16_sys(const void* p0, const void* p1,
                                                    f32x4* a, f32x4* b) {
    asm volatile("global_load_dwordx4 %0, %2, off sc0 sc1\n\t"
                 "global_load_dwordx4 %1, %3, off sc0 sc1\n\t"
                 "s_waitcnt vmcnt(0)"
                 : "=&v"(*a), "=&v"(*b) : "v"(p0), "v"(p1) : "memory");
}

// true if no f16 half of the 16B chunk equals the poison pattern
static __device__ __forceinline__ int chunk_clean(f32x4 v) {
#pragma unroll
    for (int i = 0; i < 4; ++i) {
        unsigned u = __float_as_uint(v[i]);
        if ((u & 0xFFFFu) == POISON || (u >> 16) == POISON) return 0;
    }
    return 1;
}

// ---------------- poison init: fill 3 h slots with f16 +inf ----------------
__global__ __launch_bounds__(256)
void k_poison(f16* __restrict__ hsl) {
    f32x4 v;
    const float pf = __uint_as_float((POISON << 16) | POISON);
#pragma unroll
    for (int i = 0; i < 4; ++i) v[i] = pf;
    const size_t i = ((size_t)blockIdx.x * 256 + threadIdx.x) * 8;
    if (i < (size_t)3 * HSZ) *(f32x4*)(hsl + i) = v;
}

// ---------------- x f32 -> f16 (one-time; makes proj staging conversion-free) ----
__global__ __launch_bounds__(256)
void k_xcvt(const float* __restrict__ x, f16* __restrict__ xh) {
    const size_t i = ((size_t)blockIdx.x * 256 + threadIdx.x) * 8;
    if (i < (size_t)NBATCH * NTIME * NKIN) {
        float4 v0 = *(const float4*)(x + i);
        float4 v1 = *(const float4*)(x + i + 4);
        *(f16x8*)(xh + i) = pack8(v0, v1);
    }
}

// ---------------- transpose: f32 in[512][2048] -> f16 out[2048][512] ----------------
__global__ __launch_bounds__(256)
void k_transpose(const float* __restrict__ in, f16* __restrict__ out) {
    __shared__ f16 tile[64][72];
    const int c0 = blockIdx.x * 64;
    const int r0 = blockIdx.y * 64;
    const int tid = threadIdx.x;
    {
        const int lr = tid >> 2;
        const int lc = (tid & 3) << 4;
        const float* src = in + (size_t)(r0 + lr) * NGATE + c0 + lc;
        float4 v0 = ((const float4*)src)[0];
        float4 v1 = ((const float4*)src)[1];
        float4 v2 = ((const float4*)src)[2];
        float4 v3 = ((const float4*)src)[3];
        *(f16x8*)&tile[lr][lc]     = pack8(v0, v1);
        *(f16x8*)&tile[lr][lc + 8] = pack8(v2, v3);
    }
    __syncthreads();
    {
        const int lc = tid >> 2;
        const int lr = (tid & 3) << 4;
        f16x8 a, b;
#pragma unroll
        for (int i = 0; i < 8; ++i) a[i] = tile[lr + i][lc];
#pragma unroll
        for (int i = 0; i < 8; ++i) b[i] = tile[lr + 8 + i][lc];
        f16* dst = out + (size_t)(c0 + lc) * NKIN + r0 + lr;
        *(f16x8*)dst       = a;
        *(f16x8*)(dst + 8) = b;
    }
}

// ---------------- projection (f32-x fallback, r8-verbatim) ----------------
__global__ __launch_bounds__(256)
void k_proj(const float* __restrict__ x, const f16* __restrict__ Wt,
            const float* __restrict__ bias, f16* __restrict__ xz) {
    __shared__ f16 As[128][40];
    __shared__ f16 Bs[128][40];
    const int bid = blockIdx.y * gridDim.x + blockIdx.x;   // 0..2047
    const int swz = (bid & 7) * 256 + (bid >> 3);          // XCD-contiguous chunks
    const int nb = swz & 15;
    const int tb = swz >> 4;
    const int n0 = nb * 128;
    const int tid  = threadIdx.x;
    const int lane = tid & 63;
    const int wid  = tid >> 6;
    const int wm = (wid >> 1) * 64;
    const int wn = (wid & 1) * 64;
    const int lm = lane & 15;
    const int lg = lane >> 4;

    f32x4 acc[4][4];
#pragma unroll
    for (int mi = 0; mi < 4; ++mi)
#pragma unroll
        for (int ni = 0; ni < 4; ++ni)
#pragma unroll
            for (int i = 0; i < 4; ++i) acc[mi][ni][i] = 0.0f;

    for (int kt = 0; kt < NKIN; kt += 32) {
        {
            const int brow = tid >> 1;
            const int kq   = (tid & 1) << 4;
            const float* src = x + ((size_t)brow * NTIME + tb) * NKIN + kt + kq;
            float4 v0 = ((const float4*)src)[0];
            float4 v1 = ((const float4*)src)[1];
            float4 v2 = ((const float4*)src)[2];
            float4 v3 = ((const float4*)src)[3];
            *(f16x8*)&As[brow][kq]     = pack8(v0, v1);
            *(f16x8*)&As[brow][kq + 8] = pack8(v2, v3);
        }
        {
            const int nrow = tid >> 1;
            const int kq   = (tid & 1) << 4;
            const f16* src = Wt + (size_t)(n0 + nrow) * NKIN + kt + kq;
            *(f16x8*)&Bs[nrow][kq]     = *(const f16x8*)src;
            *(f16x8*)&Bs[nrow][kq + 8] = *(const f16x8*)(src + 8);
        }
        __syncthreads();
        f16x8 a[4], b[4];
#pragma unroll
        for (int mi = 0; mi < 4; ++mi)
            a[mi] = *(const f16x8*)&As[wm + mi * 16 + lm][lg * 8];
#pragma unroll
        for (int ni = 0; ni < 4; ++ni)
            b[ni] = *(const f16x8*)&Bs[wn + ni * 16 + lm][lg * 8];
#pragma unroll
        for (int mi = 0; mi < 4; ++mi)
#pragma unroll
            for (int ni = 0; ni < 4; ++ni)
                acc[mi][ni] = __builtin_amdgcn_mfma_f32_16x16x32_f16(a[mi], b[ni], acc[mi][ni], 0, 0, 0);
        __syncthreads();
    }
#pragma unroll
    for (int mi = 0; mi < 4; ++mi) {
#pragma unroll
        for (int ni = 0; ni < 4; ++ni) {
            const int col = n0 + wn + ni * 16 + lm;
            const float bv = bias[col];
#pragma unroll
            for (int i = 0; i < 4; ++i) {
                const int brow = wm + mi * 16 + lg * 4 + i;
                xz[((size_t)tb * NBATCH + brow) * NGATE + col] = (f16)(acc[mi][ni][i] + bv);
            }
        }
    }
}

// ---------------- projection (f16-x fast path: conversion-free staging) ----------
__global__ __launch_bounds__(256)
void k_proj_f16(const f16* __restrict__ xh, const f16* __restrict__ Wt,
                const float* __restrict__ bias, f16* __restrict__ xz) {
    __shared__ f16 As[128][40];
    __shared__ f16 Bs[128][40];
    const int bid = blockIdx.y * gridDim.x + blockIdx.x;
    const int swz = (bid & 7) * 256 + (bid >> 3);
    const int nb = swz & 15;
    const int tb = swz >> 4;
    const int n0 = nb * 128;
    const int tid  = threadIdx.x;
    const int lane = tid & 63;
    const int wid  = tid >> 6;
    const int wm = (wid >> 1) * 64;
    const int wn = (wid & 1) * 64;
    const int lm = lane & 15;
    const int lg = lane >> 4;

    f32x4 acc[4][4];
#pragma unroll
    for (int mi = 0; mi < 4; ++mi)
#pragma unroll
        for (int ni = 0; ni < 4; ++ni)
#pragma unroll
            for (int i = 0; i < 4; ++i) acc[mi][ni][i] = 0.0f;

    for (int kt = 0; kt < NKIN; kt += 32) {
        {
            const int brow = tid >> 1;
            const int kq   = (tid & 1) << 4;
            const f16* src = xh + ((size_t)brow * NTIME + tb) * NKIN + kt + kq;
            *(f16x8*)&As[brow][kq]     = *(const f16x8*)src;
            *(f16x8*)&As[brow][kq + 8] = *(const f16x8*)(src + 8);
        }
        {
            const int nrow = tid >> 1;
            const int kq   = (tid & 1) << 4;
            const f16* src = Wt + (size_t)(n0 + nrow) * NKIN + kt + kq;
            *(f16x8*)&Bs[nrow][kq]     = *(const f16x8*)src;
            *(f16x8*)&Bs[nrow][kq + 8] = *(const f16x8*)(src + 8);
        }
        __syncthreads();
        f16x8 a[4], b[4];
#pragma unroll
        for (int mi = 0; mi < 4; ++mi)
            a[mi] = *(const f16x8*)&As[wm + mi * 16 + lm][lg * 8];
#pragma unroll
        for (int ni = 0; ni < 4; ++ni)
            b[ni] = *(const f16x8*)&Bs[wn + ni * 16 + lm][lg * 8];
#pragma unroll
        for (int mi = 0; mi < 4; ++mi)
#pragma unroll
            for (int ni = 0; ni < 4; ++ni)
                acc[mi][ni] = __builtin_amdgcn_mfma_f32_16x16x32_f16(a[mi], b[ni], acc[mi][ni], 0, 0, 0);
        __syncthreads();
    }
#pragma unroll
    for (int mi = 0; mi < 4; ++mi) {
#pragma unroll
        for (int ni = 0; ni < 4; ++ni) {
            const int col = n0 + wn + ni * 16 + lm;
            const float bv = bias[col];
#pragma unroll
            for (int i = 0; i < 4; ++i) {
                const int brow = wm + mi * 16 + lg * 4 + i;
                xz[((size_t)tb * NBATCH + brow) * NGATE + col] = (f16)(acc[mi][ni][i] + bv);
            }
        }
    }
}

// ---------------- persistent LSTM: poll-the-data exchange over MALL (r8-exact) ----
// 256 blocks = 16 groups x 16 slots (STATIC). Group = 8 batch rows; block = 32
// unit-cols x 4 gates (128KB U in LDS). h[t] lives in rotating slot t%3 of a
// write-once, poison-initialized buffer; consumers poll their 16B chunks until
// poison-free (sc0sc1, MALL-coherent). No flags, no drains: ~1 RTT per step.
// Depth-3 poison recycling: at step t (after poll of h[t-1]) each block poisons
// its OWN chunk of slot (t+1)%3 (holds h[t-2]; poll success proves all read it).
__global__ __launch_bounds__(256)
void k_lstm(const f16* __restrict__ xz, const f16* __restrict__ Ut,
            f16* __restrict__ hsl, float* __restrict__ out) {
    __shared__ f16 Us[128][512];     // 128 local gate-cols x 512 k, XOR-swizzled
    __shared__ f16 As[16][512];      // h rows (8 valid + 8 zero), XOR-swizzled
    __shared__ float zs[4][GROWS][33];
    const int bid = blockIdx.x;
    const int grp = bid & 15;
    const int ug  = bid >> 4;
    const int r0 = grp * GROWS;
    const int u0 = ug * 32;
    const int tid  = threadIdx.x;
    const int lane = tid & 63;
    const int g    = tid >> 6;       // wave id == gate (i,f,g,o)
    const int lm = lane & 15;
    const int lg = lane >> 4;

    // one-time: stage U-slice (swizzled). 8192 chunks of 8 f16; 32 per thread.
#pragma unroll
    for (int i = 0; i < 32; ++i) {
        const int idx = tid + i * 256;
        const int c   = idx >> 6;           // local col 0..127
        const int ck  = idx & 63;           // chunk 0..63
        const int gcol = (c >> 5) * NUNITS + u0 + (c & 31);
        f16x8 v = *(const f16x8*)(Ut + (size_t)gcol * NUNITS + ck * 8);
        *(f16x8*)&Us[c][(ck ^ (c & 7)) * 8] = v;
    }
    // zero As (t=0 uses h=0; rows 8..15 stay zero forever)
    {
        f32x4 z = {0.f, 0.f, 0.f, 0.f};
        for (int i = tid; i < 16 * 64; i += 256)
            *(f32x4*)&As[i >> 6][(i & 63) * 8] = z;
    }

    const int srow = tid >> 5;       // 0..7
    const int suu  = tid & 31;       // 0..31
    const int gidx = (r0 + srow) * NUNITS + u0 + suu;
    float c_reg = 0.0f;

    // poison chunk vector
    f32x4 pz;
    {
        const float pf = __uint_as_float((POISON << 16) | POISON);
#pragma unroll
        for (int i = 0; i < 4; ++i) pz[i] = pf;
    }

    // xz prefetch registers (t=0)
    float px[8] = {0.f, 0.f, 0.f, 0.f, 0.f, 0.f, 0.f, 0.f};
    if (lg < 2) {
        const f16* xp = xz + ((size_t)(r0 + lg * 4)) * NGATE + g * NUNITS + u0 + lm;
#pragma unroll
        for (int i = 0; i < 4; ++i) {
            px[i]     = (float)xp[(size_t)i * NGATE];
            px[4 + i] = (float)xp[(size_t)i * NGATE + 16];
        }
    }
    __syncthreads();   // Us/As visible to all waves before t=0 MFMA

    for (int t = 0; t < NTIME; ++t) {
        const f16* hin = hsl + (size_t)((t + 2) % 3) * HSZ;   // slot of h[t-1]
        f16*      hout = hsl + (size_t)(t % 3) * HSZ;         // slot of h[t]

        if (t > 0) {
            // poll-stage: spin on own 2 chunks until poison-free; result IS the data
            {
                const int row = tid >> 5;
                const int c0_ = tid & 31;
                const f16* src = hin + (size_t)(r0 + row) * NUNITS;
                f32x4 a, b;
                for (int spin = 0; spin < 65536; ++spin) {
                    load2x16_sys(src + c0_ * 8, src + (c0_ + 32) * 8, &a, &b);
                    if (chunk_clean(a) && chunk_clean(b)) break;
                }
                *(f32x4*)&As[row][(c0_ ^ (row & 7)) * 8]        = a;
                *(f32x4*)&As[row][((c0_ + 32) ^ (row & 7)) * 8] = b;
            }
            __syncthreads();
            // recycle: poison own chunk of slot (t+1)%3 (fire-and-forget; ordered
            // before our step-t+1 data write by the intervening poll vmcnt(0)s)
            if (tid < 32) {
                f16* ps = hsl + (size_t)((t + 1) % 3) * HSZ
                              + (size_t)(r0 + (tid >> 2)) * NUNITS + u0 + (tid & 3) * 8;
                store_16B_sys(ps, pz);
            }
        }

        // MFMA: wave g computes z[8 valid rows][32 cols]; split chains halve dep depth
        f32x4 acc0a, acc0b, acc1a, acc1b;
#pragma unroll
        for (int i = 0; i < 4; ++i) {
            acc0a[i] = px[i]; acc1a[i] = px[4 + i];
            acc0b[i] = 0.f;   acc1b[i] = 0.f;
        }
#pragma unroll
        for (int ks = 0; ks < 16; ks += 2) {
            const int ca0 = ((ks * 4 + lg) ^ (lm & 7)) * 8;
            const int ca1 = (((ks + 1) * 4 + lg) ^ (lm & 7)) * 8;
            f16x8 a0 = *(const f16x8*)&As[lm][ca0];
            f16x8 a1 = *(const f16x8*)&As[lm][ca1];
            f16x8 b00 = *(const f16x8*)&Us[g * 32 + lm][ca0];
            f16x8 b01 = *(const f16x8*)&Us[g * 32 + 16 + lm][ca0];
            f16x8 b10 = *(const f16x8*)&Us[g * 32 + lm][ca1];
            f16x8 b11 = *(const f16x8*)&Us[g * 32 + 16 + lm][ca1];
            acc0a = __builtin_amdgcn_mfma_f32_16x16x32_f16(a0, b00, acc0a, 0, 0, 0);
            acc1a = __builtin_amdgcn_mfma_f32_16x16x32_f16(a0, b01, acc1a, 0, 0, 0);
            acc0b = __builtin_amdgcn_mfma_f32_16x16x32_f16(a1, b10, acc0b, 0, 0, 0);
            acc1b = __builtin_amdgcn_mfma_f32_16x16x32_f16(a1, b11, acc1b, 0, 0, 0);
        }
        f32x4 acc0 = acc0a + acc0b;
        f32x4 acc1 = acc1a + acc1b;

        // prefetch next step's xz (plain cached loads; overlaps rest of step)
        {
            const int tn = (t + 1 < NTIME) ? t + 1 : t;
            if (lg < 2) {
                const f16* xp = xz + ((size_t)tn * NBATCH + r0 + lg * 4) * NGATE
                                   + g * NUNITS + u0 + lm;
#pragma unroll
                for (int i = 0; i < 4; ++i) {
                    px[i]     = (float)xp[(size_t)i * NGATE];
                    px[4 + i] = (float)xp[(size_t)i * NGATE + 16];
                }
            }
        }

        // gate exchange
        if (lg < 2) {
#pragma unroll
            for (int i = 0; i < 4; ++i) {
                zs[g][lg * 4 + i][lm]      = acc0[i];
                zs[g][lg * 4 + i][16 + lm] = acc1[i];
            }
        }
        __syncthreads();

        // state update: 256 threads = 8 rows x 32 units
        const float zi = zs[0][srow][suu];
        const float zf = zs[1][srow][suu];
        const float zg = zs[2][srow][suu];
        const float zo = zs[3][srow][suu];
        const float iv = sigmoidf_(zi);
        const float fv = sigmoidf_(zf);
        const float gv = tanhf_(zg);
        const float ov = sigmoidf_(zo);
        c_reg = fv * c_reg + iv * gv;
        const float hn = ov * tanhf_(c_reg);

        if (t == NTIME - 1) {
            out[gidx]          = hn;
            out[65536 + gidx]  = hn;
            out[131072 + gidx] = c_reg;
        } else {
            // direct fire-and-forget h store (wave-coalesced 2B sc0sc1);
            // consumers poll the data, so no drain / no flag needed
            union { f16 h; unsigned short u; } cv; cv.h = (f16)hn;
            store_u16_sys(hout + gidx, cv.u);
        }
    }
}

extern "C" void kernel_launch(void* const* d_in, const int* in_sizes, int n_in,
                              void* d_out, int out_size, void* d_ws, size_t ws_size,
                              hipStream_t stream) {
    const float* x    = (const float*)d_in[0];
    const float* W    = (const float*)d_in[1];
    const float* U    = (const float*)d_in[2];
    const float* bias = (const float*)d_in[3];
    float* out = (float*)d_out;
    char* ws = (char*)d_ws;

    size_t off = 0;
    f16* Wt = (f16*)(ws + off); off += (size_t)NGATE * NKIN * 2;
    f16* Ut = (f16*)(ws + off); off += (size_t)NGATE * NUNITS * 2;
    f16* xz = (f16*)(ws + off); off += (size_t)NTIME * NBATCH * NGATE * 2;  // [t][b][g]
    f16* hsl = (f16*)(ws + off); off += (size_t)3 * HSZ * 2;                // 3 h slots
    const size_t base_off = off;            // r8-proven footprint (~69.6 MB)
    f16* xh = (f16*)(ws + off);
    const size_t xh_off = off + (size_t)NBATCH * NTIME * NKIN * 2;          // +16 MB
    if (ws_size < base_off) return;
    const bool use_f16_proj = (ws_size >= xh_off);   // deterministic per harness

    k_poison<<<dim3(96), 256, 0, stream>>>(hsl);
    k_transpose<<<dim3(32, 8), 256, 0, stream>>>(W, Wt);
    k_transpose<<<dim3(32, 8), 256, 0, stream>>>(U, Ut);
    if (use_f16_proj) {
        k_xcvt<<<dim3(4096), 256, 0, stream>>>(x, xh);
        k_proj_f16<<<dim3(16, 128), 256, 0, stream>>>(xh, Wt, bias, xz);
    } else {
        k_proj<<<dim3(16, 128), 256, 0, stream>>>(x, Wt, bias, xz);
    }
    k_lstm<<<dim3(256), 256, 0, stream>>>(xz, Ut, hsl, out);
}

// Round 18
// 452.370 us; speedup vs baseline: 1.6621x; 1.0193x over previous
//
#include <hip/hip_runtime.h>
#include <hip/hip_bf16.h>

typedef _Float16 f16;
typedef _Float16 f16x8 __attribute__((ext_vector_type(8)));
typedef float f32x4 __attribute__((ext_vector_type(4)));

#define NBATCH 128
#define NTIME  128
#define NKIN   512
#define NUNITS 512
#define NGATE  2048

#define GROUPS 16   // batch groups (8 rows each): grp = bid & 15
#define BLKPG  16   // blocks per group (32 unit-cols each): slot = bid >> 4
#define GROWS  8    // batch rows per group
#define HSZ    (NBATCH * NUNITS)   // one h slot (f16 elems)
#define POISON 0x7C00u             // f16 +inf: impossible as h = o*tanh(c)

static __device__ __forceinline__ float sigmoidf_(float x) {
    return 1.0f / (1.0f + __expf(-x));
}
static __device__ __forceinline__ float tanhf_(float x) {
    float t = __expf(-2.0f * fabsf(x));
    float r = (1.0f - t) / (1.0f + t);
    return copysignf(r, x);
}

static __device__ __forceinline__ f16x8 pack8(float4 a, float4 b) {
    f16x8 r;
    r[0] = (f16)a.x; r[1] = (f16)a.y; r[2] = (f16)a.z; r[3] = (f16)a.w;
    r[4] = (f16)b.x; r[5] = (f16)b.y; r[6] = (f16)b.z; r[7] = (f16)b.w;
    return r;
}

// ---- MALL-coherent (sc0 sc1) ops: bypass L1+L2; device-wide; proven r3/r4/r8/r16 ----
static __device__ __forceinline__ void store_u16_sys(void* p, unsigned short v) {
    asm volatile("global_store_short %0, %1, off sc0 sc1" :: "v"(p), "v"(v) : "memory");
}
static __device__ __forceinline__ void store_16B_sys(void* p, f32x4 v) {
    asm volatile("global_store_dwordx4 %0, %1, off sc0 sc1" :: "v"(p), "v"(v) : "memory");
}
static __device__ __forceinline__ void load2x16_sys(const void* p0, const void* p1,
                                                    f32x4* a, f32x4* b) {
    asm volatile("global_load_dwordx4 %0, %2, off sc0 sc1\n\t"
                 "global_load_dwordx4 %1, %3, off sc0 sc1\n\t"
                 "s_waitcnt vmcnt(0)"
                 : "=&v"(*a), "=&v"(*b) : "v"(p0), "v"(p1) : "memory");
}

// true if no f16 half of the 16B chunk equals the poison pattern
static __device__ __forceinline__ int chunk_clean(f32x4 v) {
#pragma unroll
    for (int i = 0; i < 4; ++i) {
        unsigned u = __float_as_uint(v[i]);
        if ((u & 0xFFFFu) == POISON || (u >> 16) == POISON) return 0;
    }
    return 1;
}

// ---------------- fused prep: W/U transpose + h poison + x f32->f16 ----------------
// blocks 0..255: W transpose; 256..511: U transpose; 512..607: poison; 608..4703: xcvt
__global__ __launch_bounds__(256)
void k_prep(const float* __restrict__ W, const float* __restrict__ U,
            const float* __restrict__ x, f16* __restrict__ Wt, f16* __restrict__ Ut,
            f16* __restrict__ xh, f16* __restrict__ hsl, const int do_xcvt) {
    __shared__ f16 tile[64][72];
    const int b = blockIdx.x;
    const int tid = threadIdx.x;
    if (b < 512) {
        const float* in = (b < 256) ? W : U;
        f16* out = (b < 256) ? Wt : Ut;
        const int bb = b & 255;
        const int c0 = (bb & 31) * 64;
        const int r0 = (bb >> 5) * 64;
        {
            const int lr = tid >> 2;
            const int lc = (tid & 3) << 4;
            const float* src = in + (size_t)(r0 + lr) * NGATE + c0 + lc;
            float4 v0 = ((const float4*)src)[0];
            float4 v1 = ((const float4*)src)[1];
            float4 v2 = ((const float4*)src)[2];
            float4 v3 = ((const float4*)src)[3];
            *(f16x8*)&tile[lr][lc]     = pack8(v0, v1);
            *(f16x8*)&tile[lr][lc + 8] = pack8(v2, v3);
        }
        __syncthreads();
        {
            const int lc = tid >> 2;
            const int lr = (tid & 3) << 4;
            f16x8 a, bb2;
#pragma unroll
            for (int i = 0; i < 8; ++i) a[i] = tile[lr + i][lc];
#pragma unroll
            for (int i = 0; i < 8; ++i) bb2[i] = tile[lr + 8 + i][lc];
            f16* dst = out + (size_t)(c0 + lc) * NKIN + r0 + lr;
            *(f16x8*)dst       = a;
            *(f16x8*)(dst + 8) = bb2;
        }
    } else if (b < 608) {
        f32x4 v;
        const float pf = __uint_as_float((POISON << 16) | POISON);
#pragma unroll
        for (int i = 0; i < 4; ++i) v[i] = pf;
        const size_t i = ((size_t)(b - 512) * 256 + tid) * 8;
        if (i < (size_t)3 * HSZ) *(f32x4*)(hsl + i) = v;
    } else {
        if (!do_xcvt) return;
        const size_t i = ((size_t)(b - 608) * 256 + tid) * 8;
        if (i < (size_t)NBATCH * NTIME * NKIN) {
            float4 v0 = *(const float4*)(x + i);
            float4 v1 = *(const float4*)(x + i + 4);
            *(f16x8*)(xh + i) = pack8(v0, v1);
        }
    }
}

// ---------------- projection (f32-x fallback, r8-verbatim) ----------------
__global__ __launch_bounds__(256)
void k_proj(const float* __restrict__ x, const f16* __restrict__ Wt,
            const float* __restrict__ bias, f16* __restrict__ xz) {
    __shared__ f16 As[128][40];
    __shared__ f16 Bs[128][40];
    const int bid = blockIdx.y * gridDim.x + blockIdx.x;
    const int swz = (bid & 7) * 256 + (bid >> 3);
    const int nb = swz & 15;
    const int tb = swz >> 4;
    const int n0 = nb * 128;
    const int tid  = threadIdx.x;
    const int lane = tid & 63;
    const int wid  = tid >> 6;
    const int wm = (wid >> 1) * 64;
    const int wn = (wid & 1) * 64;
    const int lm = lane & 15;
    const int lg = lane >> 4;

    f32x4 acc[4][4];
#pragma unroll
    for (int mi = 0; mi < 4; ++mi)
#pragma unroll
        for (int ni = 0; ni < 4; ++ni)
#pragma unroll
            for (int i = 0; i < 4; ++i) acc[mi][ni][i] = 0.0f;

    for (int kt = 0; kt < NKIN; kt += 32) {
        {
            const int brow = tid >> 1;
            const int kq   = (tid & 1) << 4;
            const float* src = x + ((size_t)brow * NTIME + tb) * NKIN + kt + kq;
            float4 v0 = ((const float4*)src)[0];
            float4 v1 = ((const float4*)src)[1];
            float4 v2 = ((const float4*)src)[2];
            float4 v3 = ((const float4*)src)[3];
            *(f16x8*)&As[brow][kq]     = pack8(v0, v1);
            *(f16x8*)&As[brow][kq + 8] = pack8(v2, v3);
        }
        {
            const int nrow = tid >> 1;
            const int kq   = (tid & 1) << 4;
            const f16* src = Wt + (size_t)(n0 + nrow) * NKIN + kt + kq;
            *(f16x8*)&Bs[nrow][kq]     = *(const f16x8*)src;
            *(f16x8*)&Bs[nrow][kq + 8] = *(const f16x8*)(src + 8);
        }
        __syncthreads();
        f16x8 a[4], b[4];
#pragma unroll
        for (int mi = 0; mi < 4; ++mi)
            a[mi] = *(const f16x8*)&As[wm + mi * 16 + lm][lg * 8];
#pragma unroll
        for (int ni = 0; ni < 4; ++ni)
            b[ni] = *(const f16x8*)&Bs[wn + ni * 16 + lm][lg * 8];
#pragma unroll
        for (int mi = 0; mi < 4; ++mi)
#pragma unroll
            for (int ni = 0; ni < 4; ++ni)
                acc[mi][ni] = __builtin_amdgcn_mfma_f32_16x16x32_f16(a[mi], b[ni], acc[mi][ni], 0, 0, 0);
        __syncthreads();
    }
#pragma unroll
    for (int mi = 0; mi < 4; ++mi) {
#pragma unroll
        for (int ni = 0; ni < 4; ++ni) {
            const int col = n0 + wn + ni * 16 + lm;
            const float bv = bias[col];
#pragma unroll
            for (int i = 0; i < 4; ++i) {
                const int brow = wm + mi * 16 + lg * 4 + i;
                xz[((size_t)tb * NBATCH + brow) * NGATE + col] = (f16)(acc[mi][ni][i] + bv);
            }
        }
    }
}

// ---------------- projection (f16-x fast path, r16-proven) ----------------
__global__ __launch_bounds__(256)
void k_proj_f16(const f16* __restrict__ xh, const f16* __restrict__ Wt,
                const float* __restrict__ bias, f16* __restrict__ xz) {
    __shared__ f16 As[128][40];
    __shared__ f16 Bs[128][40];
    const int bid = blockIdx.y * gridDim.x + blockIdx.x;
    const int swz = (bid & 7) * 256 + (bid >> 3);
    const int nb = swz & 15;
    const int tb = swz >> 4;
    const int n0 = nb * 128;
    const int tid  = threadIdx.x;
    const int lane = tid & 63;
    const int wid  = tid >> 6;
    const int wm = (wid >> 1) * 64;
    const int wn = (wid & 1) * 64;
    const int lm = lane & 15;
    const int lg = lane >> 4;

    f32x4 acc[4][4];
#pragma unroll
    for (int mi = 0; mi < 4; ++mi)
#pragma unroll
        for (int ni = 0; ni < 4; ++ni)
#pragma unroll
            for (int i = 0; i < 4; ++i) acc[mi][ni][i] = 0.0f;

    for (int kt = 0; kt < NKIN; kt += 32) {
        {
            const int brow = tid >> 1;
            const int kq   = (tid & 1) << 4;
            const f16* src = xh + ((size_t)brow * NTIME + tb) * NKIN + kt + kq;
            *(f16x8*)&As[brow][kq]     = *(const f16x8*)src;
            *(f16x8*)&As[brow][kq + 8] = *(const f16x8*)(src + 8);
        }
        {
            const int nrow = tid >> 1;
            const int kq   = (tid & 1) << 4;
            const f16* src = Wt + (size_t)(n0 + nrow) * NKIN + kt + kq;
            *(f16x8*)&Bs[nrow][kq]     = *(const f16x8*)src;
            *(f16x8*)&Bs[nrow][kq + 8] = *(const f16x8*)(src + 8);
        }
        __syncthreads();
        f16x8 a[4], b[4];
#pragma unroll
        for (int mi = 0; mi < 4; ++mi)
            a[mi] = *(const f16x8*)&As[wm + mi * 16 + lm][lg * 8];
#pragma unroll
        for (int ni = 0; ni < 4; ++ni)
            b[ni] = *(const f16x8*)&Bs[wn + ni * 16 + lm][lg * 8];
#pragma unroll
        for (int mi = 0; mi < 4; ++mi)
#pragma unroll
            for (int ni = 0; ni < 4; ++ni)
                acc[mi][ni] = __builtin_amdgcn_mfma_f32_16x16x32_f16(a[mi], b[ni], acc[mi][ni], 0, 0, 0);
        __syncthreads();
    }
#pragma unroll
    for (int mi = 0; mi < 4; ++mi) {
#pragma unroll
        for (int ni = 0; ni < 4; ++ni) {
            const int col = n0 + wn + ni * 16 + lm;
            const float bv = bias[col];
#pragma unroll
            for (int i = 0; i < 4; ++i) {
                const int brow = wm + mi * 16 + lg * 4 + i;
                xz[((size_t)tb * NBATCH + brow) * NGATE + col] = (f16)(acc[mi][ni][i] + bv);
            }
        }
    }
}

// ---------------- persistent LSTM: poll-the-data exchange over MALL (r8-exact) ----
// 256 blocks = 16 groups x 16 slots (STATIC). Group = 8 batch rows; block = 32
// unit-cols x 4 gates (128KB U in LDS). h[t] lives in rotating slot t%3 of a
// write-once, poison-initialized buffer; consumers poll their 16B chunks until
// poison-free (sc0sc1, MALL-coherent). No flags, no drains: ~1 RTT per step.
// Depth-3 poison recycling: at step t (after poll of h[t-1]) each block poisons
// its OWN chunk of slot (t+1)%3 (holds h[t-2]; poll success proves all read it).
// NOTE (r17 lesson): do NOT hold in-flight load destinations across the loop
// body — compiler copies/spills of such registers read garbage (rule-18 class).
__global__ __launch_bounds__(256)
void k_lstm(const f16* __restrict__ xz, const f16* __restrict__ Ut,
            f16* __restrict__ hsl, float* __restrict__ out) {
    __shared__ f16 Us[128][512];     // 128 local gate-cols x 512 k, XOR-swizzled
    __shared__ f16 As[16][512];      // h rows (8 valid + 8 zero), XOR-swizzled
    __shared__ float zs[4][GROWS][33];
    const int bid = blockIdx.x;
    const int grp = bid & 15;
    const int ug  = bid >> 4;
    const int r0 = grp * GROWS;
    const int u0 = ug * 32;
    const int tid  = threadIdx.x;
    const int lane = tid & 63;
    const int g    = tid >> 6;       // wave id == gate (i,f,g,o)
    const int lm = lane & 15;
    const int lg = lane >> 4;

    // one-time: stage U-slice (swizzled). 8192 chunks of 8 f16; 32 per thread.
#pragma unroll
    for (int i = 0; i < 32; ++i) {
        const int idx = tid + i * 256;
        const int c   = idx >> 6;           // local col 0..127
        const int ck  = idx & 63;           // chunk 0..63
        const int gcol = (c >> 5) * NUNITS + u0 + (c & 31);
        f16x8 v = *(const f16x8*)(Ut + (size_t)gcol * NUNITS + ck * 8);
        *(f16x8*)&Us[c][(ck ^ (c & 7)) * 8] = v;
    }
    // zero As (t=0 uses h=0; rows 8..15 stay zero forever)
    {
        f32x4 z = {0.f, 0.f, 0.f, 0.f};
        for (int i = tid; i < 16 * 64; i += 256)
            *(f32x4*)&As[i >> 6][(i & 63) * 8] = z;
    }

    const int srow = tid >> 5;       // 0..7
    const int suu  = tid & 31;       // 0..31
    const int gidx = (r0 + srow) * NUNITS + u0 + suu;
    float c_reg = 0.0f;

    // poison chunk vector
    f32x4 pz;
    {
        const float pf = __uint_as_float((POISON << 16) | POISON);
#pragma unroll
        for (int i = 0; i < 4; ++i) pz[i] = pf;
    }

    // xz prefetch registers (t=0)
    float px[8] = {0.f, 0.f, 0.f, 0.f, 0.f, 0.f, 0.f, 0.f};
    if (lg < 2) {
        const f16* xp = xz + ((size_t)(r0 + lg * 4)) * NGATE + g * NUNITS + u0 + lm;
#pragma unroll
        for (int i = 0; i < 4; ++i) {
            px[i]     = (float)xp[(size_t)i * NGATE];
            px[4 + i] = (float)xp[(size_t)i * NGATE + 16];
        }
    }
    __syncthreads();   // Us/As visible to all waves before t=0 MFMA

    for (int t = 0; t < NTIME; ++t) {
        const f16* hin = hsl + (size_t)((t + 2) % 3) * HSZ;   // slot of h[t-1]
        f16*      hout = hsl + (size_t)(t % 3) * HSZ;         // slot of h[t]

        if (t > 0) {
            // poll-stage: spin on own 2 chunks until poison-free; result IS the data
            {
                const int row = tid >> 5;
                const int c0_ = tid & 31;
                const f16* src = hin + (size_t)(r0 + row) * NUNITS;
                f32x4 a, b;
                for (int spin = 0; spin < 65536; ++spin) {
                    load2x16_sys(src + c0_ * 8, src + (c0_ + 32) * 8, &a, &b);
                    if (chunk_clean(a) && chunk_clean(b)) break;
                }
                *(f32x4*)&As[row][(c0_ ^ (row & 7)) * 8]        = a;
                *(f32x4*)&As[row][((c0_ + 32) ^ (row & 7)) * 8] = b;
            }
            __syncthreads();
            // recycle: poison own chunk of slot (t+1)%3 (fire-and-forget; ordered
            // before our step-t+1 data write by the intervening poll vmcnt(0)s)
            if (tid < 32) {
                f16* ps = hsl + (size_t)((t + 1) % 3) * HSZ
                              + (size_t)(r0 + (tid >> 2)) * NUNITS + u0 + (tid & 3) * 8;
                store_16B_sys(ps, pz);
            }
        }

        // MFMA: wave g computes z[8 valid rows][32 cols]; split chains halve dep depth
        f32x4 acc0a, acc0b, acc1a, acc1b;
#pragma unroll
        for (int i = 0; i < 4; ++i) {
            acc0a[i] = px[i]; acc1a[i] = px[4 + i];
            acc0b[i] = 0.f;   acc1b[i] = 0.f;
        }
#pragma unroll
        for (int ks = 0; ks < 16; ks += 2) {
            const int ca0 = ((ks * 4 + lg) ^ (lm & 7)) * 8;
            const int ca1 = (((ks + 1) * 4 + lg) ^ (lm & 7)) * 8;
            f16x8 a0 = *(const f16x8*)&As[lm][ca0];
            f16x8 a1 = *(const f16x8*)&As[lm][ca1];
            f16x8 b00 = *(const f16x8*)&Us[g * 32 + lm][ca0];
            f16x8 b01 = *(const f16x8*)&Us[g * 32 + 16 + lm][ca0];
            f16x8 b10 = *(const f16x8*)&Us[g * 32 + lm][ca1];
            f16x8 b11 = *(const f16x8*)&Us[g * 32 + 16 + lm][ca1];
            acc0a = __builtin_amdgcn_mfma_f32_16x16x32_f16(a0, b00, acc0a, 0, 0, 0);
            acc1a = __builtin_amdgcn_mfma_f32_16x16x32_f16(a0, b01, acc1a, 0, 0, 0);
            acc0b = __builtin_amdgcn_mfma_f32_16x16x32_f16(a1, b10, acc0b, 0, 0, 0);
            acc1b = __builtin_amdgcn_mfma_f32_16x16x32_f16(a1, b11, acc1b, 0, 0, 0);
        }
        f32x4 acc0 = acc0a + acc0b;
        f32x4 acc1 = acc1a + acc1b;

        // prefetch next step's xz (plain cached loads; overlaps rest of step)
        {
            const int tn = (t + 1 < NTIME) ? t + 1 : t;
            if (lg < 2) {
                const f16* xp = xz + ((size_t)tn * NBATCH + r0 + lg * 4) * NGATE
                                   + g * NUNITS + u0 + lm;
#pragma unroll
                for (int i = 0; i < 4; ++i) {
                    px[i]     = (float)xp[(size_t)i * NGATE];
                    px[4 + i] = (float)xp[(size_t)i * NGATE + 16];
                }
            }
        }

        // gate exchange
        if (lg < 2) {
#pragma unroll
            for (int i = 0; i < 4; ++i) {
                zs[g][lg * 4 + i][lm]      = acc0[i];
                zs[g][lg * 4 + i][16 + lm] = acc1[i];
            }
        }
        __syncthreads();

        // state update: 256 threads = 8 rows x 32 units
        const float zi = zs[0][srow][suu];
        const float zf = zs[1][srow][suu];
        const float zg = zs[2][srow][suu];
        const float zo = zs[3][srow][suu];
        const float iv = sigmoidf_(zi);
        const float fv = sigmoidf_(zf);
        const float gv = tanhf_(zg);
        const float ov = sigmoidf_(zo);
        c_reg = fv * c_reg + iv * gv;
        const float hn = ov * tanhf_(c_reg);

        if (t == NTIME - 1) {
            out[gidx]          = hn;
            out[65536 + gidx]  = hn;
            out[131072 + gidx] = c_reg;
        } else {
            // direct fire-and-forget h store (wave-coalesced 2B sc0sc1);
            // consumers poll the data, so no drain / no flag needed
            union { f16 h; unsigned short u; } cv; cv.h = (f16)hn;
            store_u16_sys(hout + gidx, cv.u);
        }
    }
}

extern "C" void kernel_launch(void* const* d_in, const int* in_sizes, int n_in,
                              void* d_out, int out_size, void* d_ws, size_t ws_size,
                              hipStream_t stream) {
    const float* x    = (const float*)d_in[0];
    const float* W    = (const float*)d_in[1];
    const float* U    = (const float*)d_in[2];
    const float* bias = (const float*)d_in[3];
    float* out = (float*)d_out;
    char* ws = (char*)d_ws;

    size_t off = 0;
    f16* Wt = (f16*)(ws + off); off += (size_t)NGATE * NKIN * 2;
    f16* Ut = (f16*)(ws + off); off += (size_t)NGATE * NUNITS * 2;
    f16* xz = (f16*)(ws + off); off += (size_t)NTIME * NBATCH * NGATE * 2;  // [t][b][g]
    f16* hsl = (f16*)(ws + off); off += (size_t)3 * HSZ * 2;                // 3 h slots
    const size_t base_off = off;
    f16* xh = (f16*)(ws + off);
    const size_t xh_off = off + (size_t)NBATCH * NTIME * NKIN * 2;          // +16 MB
    if (ws_size < base_off) return;
    const bool use_f16_proj = (ws_size >= xh_off);   // deterministic per harness

    k_prep<<<dim3(4704), 256, 0, stream>>>(W, U, x, Wt, Ut, xh, hsl,
                                           use_f16_proj ? 1 : 0);
    if (use_f16_proj) {
        k_proj_f16<<<dim3(16, 128), 256, 0, stream>>>(xh, Wt, bias, xz);
    } else {
        k_proj<<<dim3(16, 128), 256, 0, stream>>>(x, Wt, bias, xz);
    }
    k_lstm<<<dim3(256), 256, 0, stream>>>(xz, Ut, hsl, out);
}